// Round 1
// baseline (1086.886 us; speedup 1.0000x reference)
//
#include <hip/hip_runtime.h>

// Problem constants (match reference)
#define N_NODES 20000
#define N_EDGES 300000
#define DIM 256
#define NUM_RELS 8
#define NUM_BASES 4
#define NCOL 2304           // (NUM_RELS + 1) * DIM  — last block is self-loop
#define LOOP_OFF 2048       // NUM_RELS * DIM

typedef float f32x4 __attribute__((ext_vector_type(4)));
typedef short s16x8 __attribute__((ext_vector_type(8)));

__device__ __forceinline__ unsigned short f2bf(float f) {
    unsigned u = __builtin_bit_cast(unsigned, f);
    u += 0x7fffu + ((u >> 16) & 1u);          // round-to-nearest-even
    return (unsigned short)(u >> 16);
}
__device__ __forceinline__ float bf2f(unsigned short h) {
    unsigned u = ((unsigned)h) << 16;
    return __builtin_bit_cast(float, u);
}

// ---------------------------------------------------------------------------
// K1: build WcatT [NCOL][DIM] bf16 (transposed so GEMM B-fragments are
// K-contiguous).  col n = r*256+o  ->  WcatT[n][i] = sum_b comp[r,b]*basis[b,i,o]
// col n = 2048+o  ->  loop_weight[i][o]
// ---------------------------------------------------------------------------
__global__ __launch_bounds__(256) void prep_w(const float* __restrict__ basis,
                                              const float* __restrict__ comp,
                                              const float* __restrict__ loopw,
                                              unsigned short* __restrict__ WT) {
    int n = blockIdx.x;          // 0..2303
    int i = threadIdx.x;         // 0..255
    float v;
    if (n < LOOP_OFF) {
        int r = n >> 8, o = n & 255;
        float acc = 0.f;
#pragma unroll
        for (int b = 0; b < NUM_BASES; ++b)
            acc += comp[r * NUM_BASES + b] * basis[(b * DIM + i) * DIM + o];
        v = acc;
    } else {
        int o = n - LOOP_OFF;
        v = loopw[i * DIM + o];
    }
    WT[n * DIM + i] = f2bf(v);
}

// ---------------------------------------------------------------------------
// K2: x (f32) -> x_bf16
// ---------------------------------------------------------------------------
__global__ __launch_bounds__(256) void prep_x(const float* __restrict__ x,
                                              unsigned short* __restrict__ xb) {
    int idx = (blockIdx.x * 256 + threadIdx.x) * 4;   // grid sized exactly
    float4 v = *reinterpret_cast<const float4*>(x + idx);
    ushort4 o;
    o.x = f2bf(v.x); o.y = f2bf(v.y); o.z = f2bf(v.z); o.w = f2bf(v.w);
    *reinterpret_cast<ushort4*>(xb + idx) = o;
}

// ---------------------------------------------------------------------------
// K3: H[M, NCOL] = x_bf16 @ Wcat   (bf16 in, bf16 out, f32 MFMA accum)
// 128x128 tile, BK=64, 4 waves (2x2), each wave 64x64 via 4x4 16x16x32 MFMAs.
// ---------------------------------------------------------------------------
#define BM 128
#define BN 128
#define BK 64
#define LDT 72   // padded LDS stride (bf16 elems): row stride 144B -> 4-bank skew

__global__ __launch_bounds__(256) void gemm_h(const unsigned short* __restrict__ Xb,
                                              const unsigned short* __restrict__ WT,
                                              unsigned short* __restrict__ H) {
    __shared__ unsigned short At[BM * LDT];
    __shared__ unsigned short Bt[BN * LDT];
    const int m0 = blockIdx.x * BM;
    const int n0 = blockIdx.y * BN;
    const int t = threadIdx.x;
    const int lane = t & 63;
    const int w = t >> 6;
    const int wr = w >> 1, wc = w & 1;

    f32x4 acc[4][4] = {};

    for (int k0 = 0; k0 < DIM; k0 += BK) {
        // stage A tile (rows of x_bf16), zero-pad past M
#pragma unroll
        for (int it = 0; it < 4; ++it) {
            int lin = (it * 256 + t) * 8;
            int row = lin >> 6;        // /64
            int col = lin & 63;
            s16x8 v = {};
            int gr = m0 + row;
            if (gr < N_NODES)
                v = *reinterpret_cast<const s16x8*>(Xb + gr * DIM + k0 + col);
            *reinterpret_cast<s16x8*>(&At[row * LDT + col]) = v;
        }
        // stage B tile (rows of WcatT = columns of Wcat)
#pragma unroll
        for (int it = 0; it < 4; ++it) {
            int lin = (it * 256 + t) * 8;
            int row = lin >> 6;
            int col = lin & 63;
            s16x8 v = *reinterpret_cast<const s16x8*>(WT + (n0 + row) * DIM + k0 + col);
            *reinterpret_cast<s16x8*>(&Bt[row * LDT + col]) = v;
        }
        __syncthreads();

#pragma unroll
        for (int kk = 0; kk < BK; kk += 32) {
            const int kb = kk + (lane >> 4) * 8;
            s16x8 af[4], bfr[4];
#pragma unroll
            for (int m = 0; m < 4; ++m)
                af[m] = *reinterpret_cast<const s16x8*>(&At[(wr * 64 + m * 16 + (lane & 15)) * LDT + kb]);
#pragma unroll
            for (int n = 0; n < 4; ++n)
                bfr[n] = *reinterpret_cast<const s16x8*>(&Bt[(wc * 64 + n * 16 + (lane & 15)) * LDT + kb]);
#pragma unroll
            for (int m = 0; m < 4; ++m)
#pragma unroll
                for (int n = 0; n < 4; ++n)
                    acc[m][n] = __builtin_amdgcn_mfma_f32_16x16x32_bf16(af[m], bfr[n], acc[m][n], 0, 0, 0);
        }
        __syncthreads();
    }

    // write C: row = (lane>>4)*4 + j, col = lane&15 within each 16x16 fragment
#pragma unroll
    for (int m = 0; m < 4; ++m) {
        int rbase = m0 + wr * 64 + m * 16 + ((lane >> 4) * 4);
#pragma unroll
        for (int j = 0; j < 4; ++j) {
            int row = rbase + j;
            if (row < N_NODES) {
#pragma unroll
                for (int n = 0; n < 4; ++n) {
                    int col = n0 + wc * 64 + n * 16 + (lane & 15);
                    H[(size_t)row * NCOL + col] = f2bf(acc[m][n][j]);
                }
            }
        }
    }
}

// ---------------------------------------------------------------------------
// K4: out = bias + H[:, loop block]   (initializes every element of d_out)
// ---------------------------------------------------------------------------
__global__ __launch_bounds__(256) void init_out(const unsigned short* __restrict__ H,
                                                const float* __restrict__ bias,
                                                float* __restrict__ out) {
    int idx = (blockIdx.x * 256 + threadIdx.x) * 4;   // grid sized exactly: N_NODES*DIM/4
    int n = idx >> 8;
    int c = idx & 255;
    ushort4 h = *reinterpret_cast<const ushort4*>(H + (size_t)n * NCOL + LOOP_OFF + c);
    float4 b = *reinterpret_cast<const float4*>(bias + c);
    float4 o;
    o.x = b.x + bf2f(h.x);
    o.y = b.y + bf2f(h.y);
    o.z = b.z + bf2f(h.z);
    o.w = b.w + bf2f(h.w);
    *reinterpret_cast<float4*>(out + idx) = o;
}

// ---------------------------------------------------------------------------
// K5: per-edge scatter: out[dst] += H[src, etype block]
// one wave per edge; 64 lanes x 4 floats
// ---------------------------------------------------------------------------
__global__ __launch_bounds__(256) void scatter_edges(const int* __restrict__ src,
                                                     const int* __restrict__ dst,
                                                     const int* __restrict__ et,
                                                     const unsigned short* __restrict__ H,
                                                     float* __restrict__ out) {
    int e = blockIdx.x * 4 + (threadIdx.x >> 6);
    if (e >= N_EDGES) return;
    int lane = threadIdx.x & 63;
    int s = src[e], d = dst[e], r = et[e];
    const unsigned short* hp = H + (size_t)s * NCOL + r * DIM + lane * 4;
    ushort4 v = *reinterpret_cast<const ushort4*>(hp);
    float* op = out + (size_t)d * DIM + lane * 4;
    atomicAdd(op + 0, bf2f(v.x));
    atomicAdd(op + 1, bf2f(v.y));
    atomicAdd(op + 2, bf2f(v.z));
    atomicAdd(op + 3, bf2f(v.w));
}

// ---------------------------------------------------------------------------
extern "C" void kernel_launch(void* const* d_in, const int* in_sizes, int n_in,
                              void* d_out, int out_size, void* d_ws, size_t ws_size,
                              hipStream_t stream) {
    const float* x      = (const float*)d_in[0];
    const int*   src    = (const int*)d_in[1];
    const int*   dst    = (const int*)d_in[2];
    const int*   etypes = (const int*)d_in[3];
    const float* basis  = (const float*)d_in[4];
    const float* comp   = (const float*)d_in[5];
    const float* loopw  = (const float*)d_in[6];
    const float* bias   = (const float*)d_in[7];
    float* out = (float*)d_out;

    // ws layout (bytes):
    //   WcatT  : NCOL*DIM*2          = 1,179,648
    //   x_bf16 : N_NODES*DIM*2       = 10,240,000
    //   H      : N_NODES*NCOL*2      = 92,160,000
    unsigned short* WT = (unsigned short*)d_ws;
    unsigned short* Xb = (unsigned short*)((char*)d_ws + (size_t)NCOL * DIM * 2);
    unsigned short* H  = (unsigned short*)((char*)d_ws + (size_t)NCOL * DIM * 2 + (size_t)N_NODES * DIM * 2);

    prep_w<<<NCOL, 256, 0, stream>>>(basis, comp, loopw, WT);
    prep_x<<<(N_NODES * DIM / 4 + 255) / 256, 256, 0, stream>>>(x, Xb);

    dim3 g((N_NODES + BM - 1) / BM, NCOL / BN);
    gemm_h<<<g, 256, 0, stream>>>(Xb, WT, H);

    init_out<<<(N_NODES * DIM / 4 + 255) / 256, 256, 0, stream>>>(H, bias, out);
    scatter_edges<<<(N_EDGES + 3) / 4, 256, 0, stream>>>(src, dst, etypes, H, out);
}

// Round 2
// 208.652 us; speedup vs baseline: 5.2091x; 5.2091x over previous
//
#include <hip/hip_runtime.h>

// Problem constants (match reference)
#define N_NODES 20000
#define N_EDGES 300000
#define DIM 256
#define NUM_RELS 8
#define NUM_BASES 4
#define NCOL 2304           // (NUM_RELS + 1) * DIM  — last block is self-loop
#define LOOP_OFF 2048       // NUM_RELS * DIM

typedef float f32x4 __attribute__((ext_vector_type(4)));
typedef short s16x8 __attribute__((ext_vector_type(8)));

__device__ __forceinline__ unsigned short f2bf(float f) {
    unsigned u = __builtin_bit_cast(unsigned, f);
    u += 0x7fffu + ((u >> 16) & 1u);          // round-to-nearest-even
    return (unsigned short)(u >> 16);
}
__device__ __forceinline__ float bf2f(unsigned short h) {
    unsigned u = ((unsigned)h) << 16;
    return __builtin_bit_cast(float, u);
}

// ---------------------------------------------------------------------------
// K1: build WcatT [NCOL][DIM] bf16 (transposed so GEMM B-fragments are
// K-contiguous).
// ---------------------------------------------------------------------------
__global__ __launch_bounds__(256) void prep_w(const float* __restrict__ basis,
                                              const float* __restrict__ comp,
                                              const float* __restrict__ loopw,
                                              unsigned short* __restrict__ WT) {
    int n = blockIdx.x;          // 0..2303
    int i = threadIdx.x;         // 0..255
    float v;
    if (n < LOOP_OFF) {
        int r = n >> 8, o = n & 255;
        float acc = 0.f;
#pragma unroll
        for (int b = 0; b < NUM_BASES; ++b)
            acc += comp[r * NUM_BASES + b] * basis[(b * DIM + i) * DIM + o];
        v = acc;
    } else {
        int o = n - LOOP_OFF;
        v = loopw[i * DIM + o];
    }
    WT[n * DIM + i] = f2bf(v);
}

// ---------------------------------------------------------------------------
// K2: x (f32) -> x_bf16
// ---------------------------------------------------------------------------
__global__ __launch_bounds__(256) void prep_x(const float* __restrict__ x,
                                              unsigned short* __restrict__ xb) {
    int idx = (blockIdx.x * 256 + threadIdx.x) * 4;
    float4 v = *reinterpret_cast<const float4*>(x + idx);
    ushort4 o;
    o.x = f2bf(v.x); o.y = f2bf(v.y); o.z = f2bf(v.z); o.w = f2bf(v.w);
    *reinterpret_cast<ushort4*>(xb + idx) = o;
}

// ---------------------------------------------------------------------------
// K3: H[M, NCOL] = x_bf16 @ Wcat   (bf16 in/out, f32 MFMA accum)
// ---------------------------------------------------------------------------
#define BM 128
#define BN 128
#define BK 64
#define LDT 72

__global__ __launch_bounds__(256) void gemm_h(const unsigned short* __restrict__ Xb,
                                              const unsigned short* __restrict__ WT,
                                              unsigned short* __restrict__ H) {
    __shared__ unsigned short At[BM * LDT];
    __shared__ unsigned short Bt[BN * LDT];
    const int m0 = blockIdx.x * BM;
    const int n0 = blockIdx.y * BN;
    const int t = threadIdx.x;
    const int lane = t & 63;
    const int w = t >> 6;
    const int wr = w >> 1, wc = w & 1;

    f32x4 acc[4][4] = {};

    for (int k0 = 0; k0 < DIM; k0 += BK) {
#pragma unroll
        for (int it = 0; it < 4; ++it) {
            int lin = (it * 256 + t) * 8;
            int row = lin >> 6;
            int col = lin & 63;
            s16x8 v = {};
            int gr = m0 + row;
            if (gr < N_NODES)
                v = *reinterpret_cast<const s16x8*>(Xb + gr * DIM + k0 + col);
            *reinterpret_cast<s16x8*>(&At[row * LDT + col]) = v;
        }
#pragma unroll
        for (int it = 0; it < 4; ++it) {
            int lin = (it * 256 + t) * 8;
            int row = lin >> 6;
            int col = lin & 63;
            s16x8 v = *reinterpret_cast<const s16x8*>(WT + (n0 + row) * DIM + k0 + col);
            *reinterpret_cast<s16x8*>(&Bt[row * LDT + col]) = v;
        }
        __syncthreads();

#pragma unroll
        for (int kk = 0; kk < BK; kk += 32) {
            const int kb = kk + (lane >> 4) * 8;
            s16x8 af[4], bfr[4];
#pragma unroll
            for (int m = 0; m < 4; ++m)
                af[m] = *reinterpret_cast<const s16x8*>(&At[(wr * 64 + m * 16 + (lane & 15)) * LDT + kb]);
#pragma unroll
            for (int n = 0; n < 4; ++n)
                bfr[n] = *reinterpret_cast<const s16x8*>(&Bt[(wc * 64 + n * 16 + (lane & 15)) * LDT + kb]);
#pragma unroll
            for (int m = 0; m < 4; ++m)
#pragma unroll
                for (int n = 0; n < 4; ++n)
                    acc[m][n] = __builtin_amdgcn_mfma_f32_16x16x32_bf16(af[m], bfr[n], acc[m][n], 0, 0, 0);
        }
        __syncthreads();
    }

#pragma unroll
    for (int m = 0; m < 4; ++m) {
        int rbase = m0 + wr * 64 + m * 16 + ((lane >> 4) * 4);
#pragma unroll
        for (int j = 0; j < 4; ++j) {
            int row = rbase + j;
            if (row < N_NODES) {
#pragma unroll
                for (int n = 0; n < 4; ++n) {
                    int col = n0 + wc * 64 + n * 16 + (lane & 15);
                    H[(size_t)row * NCOL + col] = f2bf(acc[m][n][j]);
                }
            }
        }
    }
}

// ---------------------------------------------------------------------------
// Sort chain: histogram by dst -> exclusive scan -> fill packed sorted list
// ---------------------------------------------------------------------------
__global__ __launch_bounds__(256) void hist_zero(int* __restrict__ hist) {
    int i = blockIdx.x * 256 + threadIdx.x;
    if (i < N_NODES) hist[i] = 0;
}

__global__ __launch_bounds__(256) void hist_build(const int* __restrict__ dst,
                                                  int* __restrict__ hist) {
    int e = blockIdx.x * 256 + threadIdx.x;
    if (e < N_EDGES) atomicAdd(&hist[dst[e]], 1);
}

// single block, 256 threads: exclusive scan of hist[20000] -> offsets[20001], cursor[20000]
__global__ __launch_bounds__(256) void scan_offsets(const int* __restrict__ hist,
                                                    int* __restrict__ offsets,
                                                    int* __restrict__ cursor) {
    __shared__ int partials[256];
    const int t = threadIdx.x;
    const int CH = (N_NODES + 255) / 256;   // 79
    const int base = t * CH;
    int sum = 0;
    for (int i = 0; i < CH; ++i) {
        int idx = base + i;
        if (idx < N_NODES) sum += hist[idx];
    }
    int own = sum;
    partials[t] = sum;
    __syncthreads();
    // Hillis-Steele inclusive scan
    for (int off = 1; off < 256; off <<= 1) {
        int add = (t >= off) ? partials[t - off] : 0;
        __syncthreads();
        partials[t] += add;
        __syncthreads();
    }
    int run = partials[t] - own;   // exclusive prefix for this chunk
    for (int i = 0; i < CH; ++i) {
        int idx = base + i;
        if (idx < N_NODES) {
            offsets[idx] = run;
            cursor[idx] = run;
            run += hist[idx];
        } else if (idx == N_NODES) {
            offsets[idx] = N_EDGES;
        }
    }
}

__global__ __launch_bounds__(256) void fill_sorted(const int* __restrict__ src,
                                                   const int* __restrict__ dst,
                                                   const int* __restrict__ et,
                                                   int* __restrict__ cursor,
                                                   int* __restrict__ sorted) {
    int e = blockIdx.x * 256 + threadIdx.x;
    if (e >= N_EDGES) return;
    int pos = atomicAdd(&cursor[dst[e]], 1);
    sorted[pos] = src[e] * NUM_RELS + et[e];
}

// ---------------------------------------------------------------------------
// K5: per-node aggregation: out[n] = bias + H[n, loop] + sum_{edges->n} H[src, et]
// one wave per node; lane covers 4 consecutive columns.
// ---------------------------------------------------------------------------
__global__ __launch_bounds__(256) void agg_nodes(const int* __restrict__ offsets,
                                                 const int* __restrict__ sorted,
                                                 const unsigned short* __restrict__ H,
                                                 const float* __restrict__ bias,
                                                 float* __restrict__ out) {
    int n = blockIdx.x * 4 + (threadIdx.x >> 6);   // grid exact: 20000/4 blocks
    int lane = threadIdx.x & 63;
    int c = lane * 4;

    float4 b = *reinterpret_cast<const float4*>(bias + c);
    ushort4 lh = *reinterpret_cast<const ushort4*>(H + (size_t)n * NCOL + LOOP_OFF + c);
    float a0 = b.x + bf2f(lh.x);
    float a1 = b.y + bf2f(lh.y);
    float a2 = b.z + bf2f(lh.z);
    float a3 = b.w + bf2f(lh.w);

    int beg = offsets[n], end = offsets[n + 1];
    int e = beg;
    for (; e + 1 < end; e += 2) {
        int p0 = sorted[e];
        int p1 = sorted[e + 1];
        ushort4 v0 = *reinterpret_cast<const ushort4*>(
            H + (size_t)(p0 >> 3) * NCOL + (p0 & 7) * DIM + c);
        ushort4 v1 = *reinterpret_cast<const ushort4*>(
            H + (size_t)(p1 >> 3) * NCOL + (p1 & 7) * DIM + c);
        a0 += bf2f(v0.x) + bf2f(v1.x);
        a1 += bf2f(v0.y) + bf2f(v1.y);
        a2 += bf2f(v0.z) + bf2f(v1.z);
        a3 += bf2f(v0.w) + bf2f(v1.w);
    }
    if (e < end) {
        int p0 = sorted[e];
        ushort4 v0 = *reinterpret_cast<const ushort4*>(
            H + (size_t)(p0 >> 3) * NCOL + (p0 & 7) * DIM + c);
        a0 += bf2f(v0.x);
        a1 += bf2f(v0.y);
        a2 += bf2f(v0.z);
        a3 += bf2f(v0.w);
    }
    float4 o = {a0, a1, a2, a3};
    *reinterpret_cast<float4*>(out + (size_t)n * DIM + c) = o;
}

// ---------------------------------------------------------------------------
extern "C" void kernel_launch(void* const* d_in, const int* in_sizes, int n_in,
                              void* d_out, int out_size, void* d_ws, size_t ws_size,
                              hipStream_t stream) {
    const float* x      = (const float*)d_in[0];
    const int*   src    = (const int*)d_in[1];
    const int*   dst    = (const int*)d_in[2];
    const int*   etypes = (const int*)d_in[3];
    const float* basis  = (const float*)d_in[4];
    const float* comp   = (const float*)d_in[5];
    const float* loopw  = (const float*)d_in[6];
    const float* bias   = (const float*)d_in[7];
    float* out = (float*)d_out;

    // ws layout (16B-aligned):
    char* p = (char*)d_ws;
    unsigned short* WT = (unsigned short*)p;            p += (size_t)NCOL * DIM * 2;        // 1,179,648
    unsigned short* Xb = (unsigned short*)p;            p += (size_t)N_NODES * DIM * 2;     // 10,240,000
    unsigned short* H  = (unsigned short*)p;            p += (size_t)N_NODES * NCOL * 2;    // 92,160,000
    int* hist    = (int*)p;                             p += (size_t)(N_NODES) * 4;
    int* offsets = (int*)p;                             p += (size_t)(N_NODES + 16) * 4;
    int* cursor  = (int*)p;                             p += (size_t)N_NODES * 4;
    int* sorted  = (int*)p;                             p += (size_t)N_EDGES * 4;

    prep_w<<<NCOL, 256, 0, stream>>>(basis, comp, loopw, WT);
    prep_x<<<(N_NODES * DIM / 4 + 255) / 256, 256, 0, stream>>>(x, Xb);

    // sort chain (independent of GEMM; same stream serializes fine)
    hist_zero<<<(N_NODES + 255) / 256, 256, 0, stream>>>(hist);
    hist_build<<<(N_EDGES + 255) / 256, 256, 0, stream>>>(dst, hist);
    scan_offsets<<<1, 256, 0, stream>>>(hist, offsets, cursor);
    fill_sorted<<<(N_EDGES + 255) / 256, 256, 0, stream>>>(src, dst, etypes, cursor, sorted);

    dim3 g((N_NODES + BM - 1) / BM, NCOL / BN);
    gemm_h<<<g, 256, 0, stream>>>(Xb, WT, H);

    agg_nodes<<<N_NODES / 4, 256, 0, stream>>>(offsets, sorted, H, bias, out);
}

// Round 3
// 182.455 us; speedup vs baseline: 5.9570x; 1.1436x over previous
//
#include <hip/hip_runtime.h>

// Problem constants (match reference)
#define N_NODES 20000
#define N_EDGES 300000
#define DIM 256
#define NUM_RELS 8
#define NUM_BASES 4
#define NCOL 2304           // (NUM_RELS + 1) * DIM  — last block is self-loop
#define LOOP_OFF 2048       // NUM_RELS * DIM

typedef float f32x4 __attribute__((ext_vector_type(4)));
typedef short s16x8 __attribute__((ext_vector_type(8)));

__device__ __forceinline__ unsigned short f2bf(float f) {
    unsigned u = __builtin_bit_cast(unsigned, f);
    u += 0x7fffu + ((u >> 16) & 1u);          // round-to-nearest-even
    return (unsigned short)(u >> 16);
}
__device__ __forceinline__ float bf2f(unsigned short h) {
    unsigned u = ((unsigned)h) << 16;
    return __builtin_bit_cast(float, u);
}

__device__ __forceinline__ void gload_lds16(const void* g, void* l) {
    __builtin_amdgcn_global_load_lds((const __attribute__((address_space(1))) void*)g,
                                     (__attribute__((address_space(3))) void*)l,
                                     16, 0, 0);
}

// ---------------------------------------------------------------------------
// K1: build WcatT [NCOL][DIM] bf16 (row n = output col; K contiguous)
// ---------------------------------------------------------------------------
__global__ __launch_bounds__(256) void prep_w(const float* __restrict__ basis,
                                              const float* __restrict__ comp,
                                              const float* __restrict__ loopw,
                                              unsigned short* __restrict__ WT) {
    int n = blockIdx.x;          // 0..2303
    int i = threadIdx.x;         // 0..255
    float v;
    if (n < LOOP_OFF) {
        int r = n >> 8, o = n & 255;
        float acc = 0.f;
#pragma unroll
        for (int b = 0; b < NUM_BASES; ++b)
            acc += comp[r * NUM_BASES + b] * basis[(b * DIM + i) * DIM + o];
        v = acc;
    } else {
        int o = n - LOOP_OFF;
        v = loopw[i * DIM + o];
    }
    WT[n * DIM + i] = f2bf(v);
}

// ---------------------------------------------------------------------------
// K2: x (f32) -> x_bf16, 8 elems/thread
// ---------------------------------------------------------------------------
__global__ __launch_bounds__(256) void prep_x(const float* __restrict__ x,
                                              unsigned short* __restrict__ xb) {
    int idx = (blockIdx.x * 256 + threadIdx.x) * 8;   // grid exact: N*D/8/256
    float4 v0 = *reinterpret_cast<const float4*>(x + idx);
    float4 v1 = *reinterpret_cast<const float4*>(x + idx + 4);
    s16x8 o;
    o[0] = (short)f2bf(v0.x); o[1] = (short)f2bf(v0.y);
    o[2] = (short)f2bf(v0.z); o[3] = (short)f2bf(v0.w);
    o[4] = (short)f2bf(v1.x); o[5] = (short)f2bf(v1.y);
    o[6] = (short)f2bf(v1.z); o[7] = (short)f2bf(v1.w);
    *reinterpret_cast<s16x8*>(xb + idx) = o;
}

// ---------------------------------------------------------------------------
// K3: H[M, NCOL] = x_bf16 @ Wcat  (bf16 in/out, f32 MFMA accum)
// 128x256 tile, BK=64, 512 threads (8 waves 2x4), global_load_lds staging,
// T2 XOR-swizzle (pre-swizzled global source + swizzled ds_read; rule #21).
// ---------------------------------------------------------------------------
#define BM 128
#define BN 256
#define BK 64

__global__ __launch_bounds__(512) void gemm_h(const unsigned short* __restrict__ Xb,
                                              const unsigned short* __restrict__ WT,
                                              unsigned short* __restrict__ H) {
    __shared__ unsigned short At[BM * BK];   // [128][64] linear, 16KB
    __shared__ unsigned short Bt[BN * BK];   // [256][64] linear, 32KB
    const int m0 = blockIdx.x * BM;
    const int n0 = blockIdx.y * BN;
    const int t = threadIdx.x;
    const int lane = t & 63;
    const int w = t >> 6;            // 0..7
    const int wr = w >> 2;           // 0..1
    const int wc = w & 3;            // 0..3

    const int srow = lane >> 3;      // staging: row within 8-row group
    const int sgrp = lane & 7;       // staging: 16B group within row

    f32x4 acc[4][4] = {};

#pragma unroll
    for (int k0 = 0; k0 < DIM; k0 += BK) {
        // ---- stage A (rows m0 + w*16 + is*8 + srow), clamp OOB rows ----
#pragma unroll
        for (int is = 0; is < 2; ++is) {
            int rt = w * 16 + is * 8 + srow;
            int gr = m0 + rt; if (gr > N_NODES - 1) gr = N_NODES - 1;
            int gcol = k0 + ((sgrp ^ (rt & 7)) << 3);
            gload_lds16(Xb + (size_t)gr * DIM + gcol, &At[(w * 16 + is * 8) * BK]);
        }
        // ---- stage B (rows n0 + w*32 + is*8 + srow) ----
#pragma unroll
        for (int is = 0; is < 4; ++is) {
            int rt = w * 32 + is * 8 + srow;
            int gcol = k0 + ((sgrp ^ (rt & 7)) << 3);
            gload_lds16(WT + (size_t)(n0 + rt) * DIM + gcol, &Bt[(w * 32 + is * 8) * BK]);
        }
        __syncthreads();   // drains vmcnt(0) before barrier

#pragma unroll
        for (int kk = 0; kk < BK; kk += 32) {
            const int gg = (kk >> 3) + (lane >> 4);   // global 16B-group index
            s16x8 af[4], bfr[4];
#pragma unroll
            for (int m = 0; m < 4; ++m) {
                int r = wr * 64 + m * 16 + (lane & 15);
                af[m] = *reinterpret_cast<const s16x8*>(&At[r * BK + ((gg ^ (r & 7)) << 3)]);
            }
#pragma unroll
            for (int n = 0; n < 4; ++n) {
                int r = wc * 64 + n * 16 + (lane & 15);
                bfr[n] = *reinterpret_cast<const s16x8*>(&Bt[r * BK + ((gg ^ (r & 7)) << 3)]);
            }
#pragma unroll
            for (int m = 0; m < 4; ++m)
#pragma unroll
                for (int n = 0; n < 4; ++n)
                    acc[m][n] = __builtin_amdgcn_mfma_f32_16x16x32_bf16(af[m], bfr[n], acc[m][n], 0, 0, 0);
        }
        __syncthreads();
    }

    // C-write: fragment row = (lane>>4)*4 + j, col = lane&15
#pragma unroll
    for (int m = 0; m < 4; ++m) {
        int rbase = m0 + wr * 64 + m * 16 + ((lane >> 4) * 4);
#pragma unroll
        for (int j = 0; j < 4; ++j) {
            int row = rbase + j;
            if (row < N_NODES) {
#pragma unroll
                for (int n = 0; n < 4; ++n) {
                    int col = n0 + wc * 64 + n * 16 + (lane & 15);
                    H[(size_t)row * NCOL + col] = f2bf(acc[m][n][j]);
                }
            }
        }
    }
}

// ---------------------------------------------------------------------------
// Sort chain: histogram by dst -> exclusive scan -> fill packed sorted list
// ---------------------------------------------------------------------------
__global__ __launch_bounds__(256) void hist_build(const int* __restrict__ dst,
                                                  int* __restrict__ hist) {
    int e = blockIdx.x * 256 + threadIdx.x;
    if (e < N_EDGES) atomicAdd(&hist[dst[e]], 1);
}

// single block, 256 threads: exclusive scan of hist[20000] -> offsets[20001], cursor
__global__ __launch_bounds__(256) void scan_offsets(const int* __restrict__ hist,
                                                    int* __restrict__ offsets,
                                                    int* __restrict__ cursor) {
    __shared__ int partials[256];
    const int t = threadIdx.x;
    const int CH = (N_NODES + 255) / 256;   // 79
    const int base = t * CH;
    int sum = 0;
    for (int i = 0; i < CH; ++i) {
        int idx = base + i;
        if (idx < N_NODES) sum += hist[idx];
    }
    int own = sum;
    partials[t] = sum;
    __syncthreads();
    for (int off = 1; off < 256; off <<= 1) {
        int add = (t >= off) ? partials[t - off] : 0;
        __syncthreads();
        partials[t] += add;
        __syncthreads();
    }
    int run = partials[t] - own;
    for (int i = 0; i < CH; ++i) {
        int idx = base + i;
        if (idx < N_NODES) {
            offsets[idx] = run;
            cursor[idx] = run;
            run += hist[idx];
        } else if (idx == N_NODES) {
            offsets[idx] = N_EDGES;
        }
    }
}

__global__ __launch_bounds__(256) void fill_sorted(const int* __restrict__ src,
                                                   const int* __restrict__ dst,
                                                   const int* __restrict__ et,
                                                   int* __restrict__ cursor,
                                                   int* __restrict__ sorted) {
    int e = blockIdx.x * 256 + threadIdx.x;
    if (e >= N_EDGES) return;
    int pos = atomicAdd(&cursor[dst[e]], 1);
    sorted[pos] = src[e] * NUM_RELS + et[e];
}

// ---------------------------------------------------------------------------
// K5: per-node aggregation. One wave per node; 2 edges in flight
// (half = lane>>5 picks edge parity, 32 lanes x 16B cover one 512B H row).
// ---------------------------------------------------------------------------
__global__ __launch_bounds__(256) void agg_nodes(const int* __restrict__ offsets,
                                                 const int* __restrict__ sorted,
                                                 const unsigned short* __restrict__ H,
                                                 const float* __restrict__ bias,
                                                 float* __restrict__ out) {
    int n = blockIdx.x * 4 + (threadIdx.x >> 6);   // grid exact: 5000 blocks
    int lane = threadIdx.x & 63;
    int half = lane >> 5;
    int l = lane & 31;
    int c = l * 8;

    float a[8] = {0.f, 0.f, 0.f, 0.f, 0.f, 0.f, 0.f, 0.f};
    int beg = offsets[n], end = offsets[n + 1];
    for (int e = beg + half; e < end; e += 2) {
        int p = sorted[e];
        s16x8 v = *reinterpret_cast<const s16x8*>(
            H + (size_t)(p >> 3) * NCOL + (p & 7) * DIM + c);
#pragma unroll
        for (int k = 0; k < 8; ++k) a[k] += bf2f((unsigned short)v[k]);
    }
    // combine the two halves
#pragma unroll
    for (int k = 0; k < 8; ++k) a[k] += __shfl_xor(a[k], 32, 64);

    if (half == 0) {
        s16x8 lh = *reinterpret_cast<const s16x8*>(H + (size_t)n * NCOL + LOOP_OFF + c);
        float4 b0 = *reinterpret_cast<const float4*>(bias + c);
        float4 b1 = *reinterpret_cast<const float4*>(bias + c + 4);
        float4 o0, o1;
        o0.x = a[0] + b0.x + bf2f((unsigned short)lh[0]);
        o0.y = a[1] + b0.y + bf2f((unsigned short)lh[1]);
        o0.z = a[2] + b0.z + bf2f((unsigned short)lh[2]);
        o0.w = a[3] + b0.w + bf2f((unsigned short)lh[3]);
        o1.x = a[4] + b1.x + bf2f((unsigned short)lh[4]);
        o1.y = a[5] + b1.y + bf2f((unsigned short)lh[5]);
        o1.z = a[6] + b1.z + bf2f((unsigned short)lh[6]);
        o1.w = a[7] + b1.w + bf2f((unsigned short)lh[7]);
        *reinterpret_cast<float4*>(out + (size_t)n * DIM + c) = o0;
        *reinterpret_cast<float4*>(out + (size_t)n * DIM + c + 4) = o1;
    }
}

// ---------------------------------------------------------------------------
extern "C" void kernel_launch(void* const* d_in, const int* in_sizes, int n_in,
                              void* d_out, int out_size, void* d_ws, size_t ws_size,
                              hipStream_t stream) {
    const float* x      = (const float*)d_in[0];
    const int*   src    = (const int*)d_in[1];
    const int*   dst    = (const int*)d_in[2];
    const int*   etypes = (const int*)d_in[3];
    const float* basis  = (const float*)d_in[4];
    const float* comp   = (const float*)d_in[5];
    const float* loopw  = (const float*)d_in[6];
    const float* bias   = (const float*)d_in[7];
    float* out = (float*)d_out;

    char* p = (char*)d_ws;
    unsigned short* WT = (unsigned short*)p;            p += (size_t)NCOL * DIM * 2;
    unsigned short* Xb = (unsigned short*)p;            p += (size_t)N_NODES * DIM * 2;
    unsigned short* H  = (unsigned short*)p;            p += (size_t)N_NODES * NCOL * 2;
    int* hist    = (int*)p;                             p += (size_t)N_NODES * 4;
    int* offsets = (int*)p;                             p += (size_t)(N_NODES + 16) * 4;
    int* cursor  = (int*)p;                             p += (size_t)N_NODES * 4;
    int* sorted  = (int*)p;                             p += (size_t)N_EDGES * 4;

    prep_w<<<NCOL, 256, 0, stream>>>(basis, comp, loopw, WT);
    prep_x<<<N_NODES * DIM / 8 / 256, 256, 0, stream>>>(x, Xb);

    hipMemsetAsync(hist, 0, (size_t)N_NODES * 4, stream);
    hist_build<<<(N_EDGES + 255) / 256, 256, 0, stream>>>(dst, hist);
    scan_offsets<<<1, 256, 0, stream>>>(hist, offsets, cursor);
    fill_sorted<<<(N_EDGES + 255) / 256, 256, 0, stream>>>(src, dst, etypes, cursor, sorted);

    dim3 g((N_NODES + BM - 1) / BM, NCOL / BN);
    gemm_h<<<g, 512, 0, stream>>>(Xb, WT, H);

    agg_nodes<<<N_NODES / 4, 256, 0, stream>>>(offsets, sorted, H, bias, out);
}

// Round 4
// 133.634 us; speedup vs baseline: 8.1333x; 1.3653x over previous
//
#include <hip/hip_runtime.h>

// Problem constants (match reference)
#define N_NODES 20000
#define N_EDGES 300000
#define DIM 256
#define NUM_RELS 8
#define NUM_BASES 4
#define NCOL 2304           // (NUM_RELS + 1) * DIM  — last block is self-loop
#define LOOP_OFF 2048       // NUM_RELS * DIM
#define NB 79               // (N_NODES + 255) / 256

typedef float f32x4 __attribute__((ext_vector_type(4)));
typedef short s16x8 __attribute__((ext_vector_type(8)));

__device__ __forceinline__ unsigned short f2bf(float f) {
    unsigned u = __builtin_bit_cast(unsigned, f);
    u += 0x7fffu + ((u >> 16) & 1u);          // round-to-nearest-even
    return (unsigned short)(u >> 16);
}
__device__ __forceinline__ float bf2f(unsigned short h) {
    unsigned u = ((unsigned)h) << 16;
    return __builtin_bit_cast(float, u);
}

__device__ __forceinline__ void gload_lds16(const void* g, void* l) {
    __builtin_amdgcn_global_load_lds((const __attribute__((address_space(1))) void*)g,
                                     (__attribute__((address_space(3))) void*)l,
                                     16, 0, 0);
}

// ---------------------------------------------------------------------------
// K1: build WcatT [NCOL][DIM] bf16 (row n = output col; K contiguous)
// ---------------------------------------------------------------------------
__global__ __launch_bounds__(256) void prep_w(const float* __restrict__ basis,
                                              const float* __restrict__ comp,
                                              const float* __restrict__ loopw,
                                              unsigned short* __restrict__ WT) {
    int n = blockIdx.x;          // 0..2303
    int i = threadIdx.x;         // 0..255
    float v;
    if (n < LOOP_OFF) {
        int r = n >> 8, o = n & 255;
        float acc = 0.f;
#pragma unroll
        for (int b = 0; b < NUM_BASES; ++b)
            acc += comp[r * NUM_BASES + b] * basis[(b * DIM + i) * DIM + o];
        v = acc;
    } else {
        int o = n - LOOP_OFF;
        v = loopw[i * DIM + o];
    }
    WT[n * DIM + i] = f2bf(v);
}

// ---------------------------------------------------------------------------
// K2: x (f32) -> x_bf16, 8 elems/thread
// ---------------------------------------------------------------------------
__global__ __launch_bounds__(256) void prep_x(const float* __restrict__ x,
                                              unsigned short* __restrict__ xb) {
    int idx = (blockIdx.x * 256 + threadIdx.x) * 8;   // grid exact: N*D/8/256
    float4 v0 = *reinterpret_cast<const float4*>(x + idx);
    float4 v1 = *reinterpret_cast<const float4*>(x + idx + 4);
    s16x8 o;
    o[0] = (short)f2bf(v0.x); o[1] = (short)f2bf(v0.y);
    o[2] = (short)f2bf(v0.z); o[3] = (short)f2bf(v0.w);
    o[4] = (short)f2bf(v1.x); o[5] = (short)f2bf(v1.y);
    o[6] = (short)f2bf(v1.z); o[7] = (short)f2bf(v1.w);
    *reinterpret_cast<s16x8*>(xb + idx) = o;
}

// ---------------------------------------------------------------------------
// K3: H[M, NCOL] = x_bf16 @ Wcat  (bf16 in/out, f32 MFMA accum)
// 128x256 tile, BK=64, 512 threads (8 waves 2x4), global_load_lds staging,
// T2 XOR-swizzle (pre-swizzled global source + swizzled ds_read; rule #21).
// ---------------------------------------------------------------------------
#define BM 128
#define BN 256
#define BK 64

__global__ __launch_bounds__(512) void gemm_h(const unsigned short* __restrict__ Xb,
                                              const unsigned short* __restrict__ WT,
                                              unsigned short* __restrict__ H) {
    __shared__ unsigned short At[BM * BK];   // [128][64] linear, 16KB
    __shared__ unsigned short Bt[BN * BK];   // [256][64] linear, 32KB
    const int m0 = blockIdx.x * BM;
    const int n0 = blockIdx.y * BN;
    const int t = threadIdx.x;
    const int lane = t & 63;
    const int w = t >> 6;            // 0..7
    const int wr = w >> 2;           // 0..1
    const int wc = w & 3;            // 0..3

    const int srow = lane >> 3;      // staging: row within 8-row group
    const int sgrp = lane & 7;       // staging: 16B group within row

    f32x4 acc[4][4] = {};

#pragma unroll
    for (int k0 = 0; k0 < DIM; k0 += BK) {
        // ---- stage A (rows m0 + w*16 + is*8 + srow), clamp OOB rows ----
#pragma unroll
        for (int is = 0; is < 2; ++is) {
            int rt = w * 16 + is * 8 + srow;
            int gr = m0 + rt; if (gr > N_NODES - 1) gr = N_NODES - 1;
            int gcol = k0 + ((sgrp ^ (rt & 7)) << 3);
            gload_lds16(Xb + (size_t)gr * DIM + gcol, &At[(w * 16 + is * 8) * BK]);
        }
        // ---- stage B (rows n0 + w*32 + is*8 + srow) ----
#pragma unroll
        for (int is = 0; is < 4; ++is) {
            int rt = w * 32 + is * 8 + srow;
            int gcol = k0 + ((sgrp ^ (rt & 7)) << 3);
            gload_lds16(WT + (size_t)(n0 + rt) * DIM + gcol, &Bt[(w * 32 + is * 8) * BK]);
        }
        __syncthreads();   // drains vmcnt(0) before barrier

#pragma unroll
        for (int kk = 0; kk < BK; kk += 32) {
            const int gg = (kk >> 3) + (lane >> 4);   // global 16B-group index
            s16x8 af[4], bfr[4];
#pragma unroll
            for (int m = 0; m < 4; ++m) {
                int r = wr * 64 + m * 16 + (lane & 15);
                af[m] = *reinterpret_cast<const s16x8*>(&At[r * BK + ((gg ^ (r & 7)) << 3)]);
            }
#pragma unroll
            for (int n = 0; n < 4; ++n) {
                int r = wc * 64 + n * 16 + (lane & 15);
                bfr[n] = *reinterpret_cast<const s16x8*>(&Bt[r * BK + ((gg ^ (r & 7)) << 3)]);
            }
#pragma unroll
            for (int m = 0; m < 4; ++m)
#pragma unroll
                for (int n = 0; n < 4; ++n)
                    acc[m][n] = __builtin_amdgcn_mfma_f32_16x16x32_bf16(af[m], bfr[n], acc[m][n], 0, 0, 0);
        }
        __syncthreads();
    }

    // C-write: fragment row = (lane>>4)*4 + j, col = lane&15
#pragma unroll
    for (int m = 0; m < 4; ++m) {
        int rbase = m0 + wr * 64 + m * 16 + ((lane >> 4) * 4);
#pragma unroll
        for (int j = 0; j < 4; ++j) {
            int row = rbase + j;
            if (row < N_NODES) {
#pragma unroll
                for (int n = 0; n < 4; ++n) {
                    int col = n0 + wc * 64 + n * 16 + (lane & 15);
                    H[(size_t)row * NCOL + col] = f2bf(acc[m][n][j]);
                }
            }
        }
    }
}

// ---------------------------------------------------------------------------
// Sort chain: histogram by dst -> hierarchical exclusive scan -> fill sorted
// ---------------------------------------------------------------------------
__global__ __launch_bounds__(256) void hist_build(const int* __restrict__ dst,
                                                  int* __restrict__ hist) {
    int e = blockIdx.x * 256 + threadIdx.x;
    if (e < N_EDGES) atomicAdd(&hist[dst[e]], 1);
}

// A: per-256-chunk sums
__global__ __launch_bounds__(256) void hist_block_sums(const int* __restrict__ hist,
                                                       int* __restrict__ bsum) {
    int i = blockIdx.x * 256 + threadIdx.x;
    int v = (i < N_NODES) ? hist[i] : 0;
#pragma unroll
    for (int off = 32; off; off >>= 1) v += __shfl_down(v, off, 64);
    __shared__ int ws[4];
    if ((threadIdx.x & 63) == 0) ws[threadIdx.x >> 6] = v;
    __syncthreads();
    if (threadIdx.x == 0) bsum[blockIdx.x] = ws[0] + ws[1] + ws[2] + ws[3];
}

// B: exclusive scan of the NB partials (in place), 1 block x 128
__global__ __launch_bounds__(128) void scan_bsums(int* __restrict__ bsum) {
    __shared__ int s[128];
    int t = threadIdx.x;
    int v = (t < NB) ? bsum[t] : 0;
    s[t] = v;
    __syncthreads();
    for (int off = 1; off < 128; off <<= 1) {
        int a = (t >= off) ? s[t - off] : 0;
        __syncthreads();
        s[t] += a;
        __syncthreads();
    }
    if (t < NB) bsum[t] = s[t] - v;   // exclusive
}

// C: block-local exclusive scan + chunk offset -> offsets, cursor
__global__ __launch_bounds__(256) void scan_final(const int* __restrict__ hist,
                                                  const int* __restrict__ bsum,
                                                  int* __restrict__ offsets,
                                                  int* __restrict__ cursor) {
    __shared__ int s[256];
    int t = threadIdx.x;
    int i = blockIdx.x * 256 + t;
    int v = (i < N_NODES) ? hist[i] : 0;
    s[t] = v;
    __syncthreads();
    for (int off = 1; off < 256; off <<= 1) {
        int a = (t >= off) ? s[t - off] : 0;
        __syncthreads();
        s[t] += a;
        __syncthreads();
    }
    int excl = s[t] - v + bsum[blockIdx.x];
    if (i < N_NODES) {
        offsets[i] = excl;
        cursor[i] = excl;
    }
    if (i == N_NODES - 1) offsets[N_NODES] = N_EDGES;
}

__global__ __launch_bounds__(256) void fill_sorted(const int* __restrict__ src,
                                                   const int* __restrict__ dst,
                                                   const int* __restrict__ et,
                                                   int* __restrict__ cursor,
                                                   int* __restrict__ sorted) {
    int e = blockIdx.x * 256 + threadIdx.x;
    if (e >= N_EDGES) return;
    int pos = atomicAdd(&cursor[dst[e]], 1);
    sorted[pos] = src[e] * NUM_RELS + et[e];
}

// ---------------------------------------------------------------------------
// K5: per-node aggregation. One wave per node; 2 edges in flight
// (half = lane>>5 picks edge parity, 32 lanes x 16B cover one 512B H row).
// ---------------------------------------------------------------------------
__global__ __launch_bounds__(256) void agg_nodes(const int* __restrict__ offsets,
                                                 const int* __restrict__ sorted,
                                                 const unsigned short* __restrict__ H,
                                                 const float* __restrict__ bias,
                                                 float* __restrict__ out) {
    int n = blockIdx.x * 4 + (threadIdx.x >> 6);   // grid exact: 5000 blocks
    int lane = threadIdx.x & 63;
    int half = lane >> 5;
    int l = lane & 31;
    int c = l * 8;

    float a[8] = {0.f, 0.f, 0.f, 0.f, 0.f, 0.f, 0.f, 0.f};
    int beg = offsets[n], end = offsets[n + 1];
    for (int e = beg + half; e < end; e += 2) {
        int p = sorted[e];
        s16x8 v = *reinterpret_cast<const s16x8*>(
            H + (size_t)(p >> 3) * NCOL + (p & 7) * DIM + c);
#pragma unroll
        for (int k = 0; k < 8; ++k) a[k] += bf2f((unsigned short)v[k]);
    }
#pragma unroll
    for (int k = 0; k < 8; ++k) a[k] += __shfl_xor(a[k], 32, 64);

    if (half == 0) {
        s16x8 lh = *reinterpret_cast<const s16x8*>(H + (size_t)n * NCOL + LOOP_OFF + c);
        float4 b0 = *reinterpret_cast<const float4*>(bias + c);
        float4 b1 = *reinterpret_cast<const float4*>(bias + c + 4);
        float4 o0, o1;
        o0.x = a[0] + b0.x + bf2f((unsigned short)lh[0]);
        o0.y = a[1] + b0.y + bf2f((unsigned short)lh[1]);
        o0.z = a[2] + b0.z + bf2f((unsigned short)lh[2]);
        o0.w = a[3] + b0.w + bf2f((unsigned short)lh[3]);
        o1.x = a[4] + b1.x + bf2f((unsigned short)lh[4]);
        o1.y = a[5] + b1.y + bf2f((unsigned short)lh[5]);
        o1.z = a[6] + b1.z + bf2f((unsigned short)lh[6]);
        o1.w = a[7] + b1.w + bf2f((unsigned short)lh[7]);
        *reinterpret_cast<float4*>(out + (size_t)n * DIM + c) = o0;
        *reinterpret_cast<float4*>(out + (size_t)n * DIM + c + 4) = o1;
    }
}

// ---------------------------------------------------------------------------
extern "C" void kernel_launch(void* const* d_in, const int* in_sizes, int n_in,
                              void* d_out, int out_size, void* d_ws, size_t ws_size,
                              hipStream_t stream) {
    const float* x      = (const float*)d_in[0];
    const int*   src    = (const int*)d_in[1];
    const int*   dst    = (const int*)d_in[2];
    const int*   etypes = (const int*)d_in[3];
    const float* basis  = (const float*)d_in[4];
    const float* comp   = (const float*)d_in[5];
    const float* loopw  = (const float*)d_in[6];
    const float* bias   = (const float*)d_in[7];
    float* out = (float*)d_out;

    char* p = (char*)d_ws;
    unsigned short* WT = (unsigned short*)p;            p += (size_t)NCOL * DIM * 2;
    unsigned short* Xb = (unsigned short*)p;            p += (size_t)N_NODES * DIM * 2;
    unsigned short* H  = (unsigned short*)p;            p += (size_t)N_NODES * NCOL * 2;
    int* hist    = (int*)p;                             p += (size_t)N_NODES * 4;
    int* offsets = (int*)p;                             p += (size_t)(N_NODES + 16) * 4;
    int* cursor  = (int*)p;                             p += (size_t)N_NODES * 4;
    int* sorted  = (int*)p;                             p += (size_t)N_EDGES * 4;
    int* bsum    = (int*)p;                             p += (size_t)(NB + 1) * 4;

    prep_w<<<NCOL, 256, 0, stream>>>(basis, comp, loopw, WT);
    prep_x<<<N_NODES * DIM / 8 / 256, 256, 0, stream>>>(x, Xb);

    hipMemsetAsync(hist, 0, (size_t)N_NODES * 4, stream);
    hist_build<<<(N_EDGES + 255) / 256, 256, 0, stream>>>(dst, hist);
    hist_block_sums<<<NB, 256, 0, stream>>>(hist, bsum);
    scan_bsums<<<1, 128, 0, stream>>>(bsum);
    scan_final<<<NB, 256, 0, stream>>>(hist, bsum, offsets, cursor);
    fill_sorted<<<(N_EDGES + 255) / 256, 256, 0, stream>>>(src, dst, etypes, cursor, sorted);

    dim3 g((N_NODES + BM - 1) / BM, NCOL / BN);
    gemm_h<<<g, 512, 0, stream>>>(Xb, WT, H);

    agg_nodes<<<N_NODES / 4, 256, 0, stream>>>(offsets, sorted, H, bias, out);
}

// Round 5
// 122.562 us; speedup vs baseline: 8.8680x; 1.0903x over previous
//
#include <hip/hip_runtime.h>

// Problem constants (match reference)
#define N_NODES 20000
#define N_EDGES 300000
#define DIM 256
#define NUM_RELS 8
#define NUM_BASES 4
#define NB 79               // (N_NODES + 255) / 256
#define K2 1280             // GEMM K: 4 basis blocks (1024) + x block (256)
#define TROW 1024           // T row length (4 * 256)

typedef float f32x4 __attribute__((ext_vector_type(4)));
typedef short s16x8 __attribute__((ext_vector_type(8)));

__device__ __forceinline__ unsigned short f2bf(float f) {
    unsigned u = __builtin_bit_cast(unsigned, f);
    u += 0x7fffu + ((u >> 16) & 1u);          // round-to-nearest-even
    return (unsigned short)(u >> 16);
}
__device__ __forceinline__ float bf2f(unsigned short h) {
    unsigned u = ((unsigned)h) << 16;
    return __builtin_bit_cast(float, u);
}

__device__ __forceinline__ void gload_lds16(const void* g, void* l) {
    __builtin_amdgcn_global_load_lds((const __attribute__((address_space(1))) void*)g,
                                     (__attribute__((address_space(3))) void*)l,
                                     16, 0, 0);
}

// ---------------------------------------------------------------------------
// K1: W2[o][k] bf16, o in [0,256) output col, k in [0,1280).
//   k = b*256+i  -> basis[b][i][o];  k = 1024+i -> loop_weight[i][o]
// ---------------------------------------------------------------------------
__global__ __launch_bounds__(256) void prep_w2(const float* __restrict__ basis,
                                               const float* __restrict__ loopw,
                                               unsigned short* __restrict__ W2) {
    int o = blockIdx.x;      // 0..255
    int i = threadIdx.x;     // 0..255
#pragma unroll
    for (int b = 0; b < NUM_BASES; ++b)
        W2[(size_t)o * K2 + b * 256 + i] = f2bf(basis[((size_t)b * 256 + i) * 256 + o]);
    W2[(size_t)o * K2 + 1024 + i] = f2bf(loopw[(size_t)i * 256 + o]);
}

// ---------------------------------------------------------------------------
// K2: x (f32) -> x_bf16, 8 elems/thread
// ---------------------------------------------------------------------------
__global__ __launch_bounds__(256) void prep_x(const float* __restrict__ x,
                                              unsigned short* __restrict__ xb) {
    int idx = (blockIdx.x * 256 + threadIdx.x) * 8;   // grid exact
    float4 v0 = *reinterpret_cast<const float4*>(x + idx);
    float4 v1 = *reinterpret_cast<const float4*>(x + idx + 4);
    s16x8 o;
    o[0] = (short)f2bf(v0.x); o[1] = (short)f2bf(v0.y);
    o[2] = (short)f2bf(v0.z); o[3] = (short)f2bf(v0.w);
    o[4] = (short)f2bf(v1.x); o[5] = (short)f2bf(v1.y);
    o[6] = (short)f2bf(v1.z); o[7] = (short)f2bf(v1.w);
    *reinterpret_cast<s16x8*>(xb + idx) = o;
}

// ---------------------------------------------------------------------------
// Sort chain: histogram by dst -> hierarchical exclusive scan -> fill sorted
// ---------------------------------------------------------------------------
__global__ __launch_bounds__(256) void hist_build(const int* __restrict__ dst,
                                                  int* __restrict__ hist) {
    int e = blockIdx.x * 256 + threadIdx.x;
    if (e < N_EDGES) atomicAdd(&hist[dst[e]], 1);
}

__global__ __launch_bounds__(256) void hist_block_sums(const int* __restrict__ hist,
                                                       int* __restrict__ bsum) {
    int i = blockIdx.x * 256 + threadIdx.x;
    int v = (i < N_NODES) ? hist[i] : 0;
#pragma unroll
    for (int off = 32; off; off >>= 1) v += __shfl_down(v, off, 64);
    __shared__ int ws[4];
    if ((threadIdx.x & 63) == 0) ws[threadIdx.x >> 6] = v;
    __syncthreads();
    if (threadIdx.x == 0) bsum[blockIdx.x] = ws[0] + ws[1] + ws[2] + ws[3];
}

__global__ __launch_bounds__(128) void scan_bsums(int* __restrict__ bsum) {
    __shared__ int s[128];
    int t = threadIdx.x;
    int v = (t < NB) ? bsum[t] : 0;
    s[t] = v;
    __syncthreads();
    for (int off = 1; off < 128; off <<= 1) {
        int a = (t >= off) ? s[t - off] : 0;
        __syncthreads();
        s[t] += a;
        __syncthreads();
    }
    if (t < NB) bsum[t] = s[t] - v;   // exclusive
}

__global__ __launch_bounds__(256) void scan_final(const int* __restrict__ hist,
                                                  const int* __restrict__ bsum,
                                                  int* __restrict__ offsets,
                                                  int* __restrict__ cursor) {
    __shared__ int s[256];
    int t = threadIdx.x;
    int i = blockIdx.x * 256 + t;
    int v = (i < N_NODES) ? hist[i] : 0;
    s[t] = v;
    __syncthreads();
    for (int off = 1; off < 256; off <<= 1) {
        int a = (t >= off) ? s[t - off] : 0;
        __syncthreads();
        s[t] += a;
        __syncthreads();
    }
    int excl = s[t] - v + bsum[blockIdx.x];
    if (i < N_NODES) {
        offsets[i] = excl;
        cursor[i] = excl;
    }
    if (i == N_NODES - 1) offsets[N_NODES] = N_EDGES;
}

__global__ __launch_bounds__(256) void fill_sorted(const int* __restrict__ src,
                                                   const int* __restrict__ dst,
                                                   const int* __restrict__ et,
                                                   int* __restrict__ cursor,
                                                   int* __restrict__ sorted) {
    int e = blockIdx.x * 256 + threadIdx.x;
    if (e >= N_EDGES) return;
    int pos = atomicAdd(&cursor[dst[e]], 1);
    sorted[pos] = src[e] * NUM_RELS + et[e];
}

// ---------------------------------------------------------------------------
// K3: gather: T[d, b*256+j] = sum_{e->d} comp[et_e, b] * x_bf16[src_e, j]
// One wave per node; each lane covers 4 consecutive j; acc[4 bases][4] in regs.
// ---------------------------------------------------------------------------
__global__ __launch_bounds__(256) void gather_T(const int* __restrict__ offsets,
                                                const int* __restrict__ sorted,
                                                const unsigned short* __restrict__ Xb,
                                                const float* __restrict__ comp,
                                                unsigned short* __restrict__ T) {
    int n = blockIdx.x * 4 + (threadIdx.x >> 6);   // grid exact: 5000 blocks
    int lane = threadIdx.x & 63;
    int c = lane * 4;

    float acc[NUM_BASES][4] = {};
    int beg = offsets[n], end = offsets[n + 1];
    int e = beg;
    for (; e + 1 < end; e += 2) {
        int p0 = sorted[e], p1 = sorted[e + 1];
        ushort4 v0 = *reinterpret_cast<const ushort4*>(Xb + (size_t)(p0 >> 3) * DIM + c);
        ushort4 v1 = *reinterpret_cast<const ushort4*>(Xb + (size_t)(p1 >> 3) * DIM + c);
        float4 c0 = *reinterpret_cast<const float4*>(comp + (p0 & 7) * 4);
        float4 c1 = *reinterpret_cast<const float4*>(comp + (p1 & 7) * 4);
        float x0[4] = {bf2f(v0.x), bf2f(v0.y), bf2f(v0.z), bf2f(v0.w)};
        float x1[4] = {bf2f(v1.x), bf2f(v1.y), bf2f(v1.z), bf2f(v1.w)};
        float cw0[4] = {c0.x, c0.y, c0.z, c0.w};
        float cw1[4] = {c1.x, c1.y, c1.z, c1.w};
#pragma unroll
        for (int b = 0; b < NUM_BASES; ++b)
#pragma unroll
            for (int j = 0; j < 4; ++j)
                acc[b][j] += cw0[b] * x0[j] + cw1[b] * x1[j];
    }
    if (e < end) {
        int p0 = sorted[e];
        ushort4 v0 = *reinterpret_cast<const ushort4*>(Xb + (size_t)(p0 >> 3) * DIM + c);
        float4 c0 = *reinterpret_cast<const float4*>(comp + (p0 & 7) * 4);
        float x0[4] = {bf2f(v0.x), bf2f(v0.y), bf2f(v0.z), bf2f(v0.w)};
        float cw0[4] = {c0.x, c0.y, c0.z, c0.w};
#pragma unroll
        for (int b = 0; b < NUM_BASES; ++b)
#pragma unroll
            for (int j = 0; j < 4; ++j)
                acc[b][j] += cw0[b] * x0[j];
    }
#pragma unroll
    for (int b = 0; b < NUM_BASES; ++b) {
        ushort4 o;
        o.x = f2bf(acc[b][0]); o.y = f2bf(acc[b][1]);
        o.z = f2bf(acc[b][2]); o.w = f2bf(acc[b][3]);
        *reinterpret_cast<ushort4*>(T + (size_t)n * TROW + b * 256 + c) = o;
    }
}

// ---------------------------------------------------------------------------
// K4: out[m, o] = sum_k A[m, k] * W2[o, k] + bias[o]
//   A = [T | x_bf16] (K=1280, source switch at k=1024).
// 128x256 tile (one N block), BK=64, 512 threads (8 waves 2x4),
// global_load_lds + XOR swizzle, 2-phase double-buffered LDS.
// ---------------------------------------------------------------------------
#define BM 128
#define BN 256
#define BK 64
#define NT 20   // K2 / BK

__global__ __launch_bounds__(512) void gemm_out(const unsigned short* __restrict__ Tb,
                                                const unsigned short* __restrict__ Xb,
                                                const unsigned short* __restrict__ W2,
                                                const float* __restrict__ bias,
                                                float* __restrict__ out) {
    __shared__ unsigned short At[2][BM * BK];   // 2 x 16KB
    __shared__ unsigned short Bt[2][BN * BK];   // 2 x 32KB
    const int m0 = blockIdx.x * BM;
    const int t = threadIdx.x;
    const int lane = t & 63;
    const int w = t >> 6;            // 0..7
    const int wr = w >> 2;           // 0..1
    const int wc = w & 3;            // 0..3
    const int srow = lane >> 3;      // 0..7
    const int sgrp = lane & 7;       // 0..7

    f32x4 acc[4][4] = {};

    auto stage = [&](int kt, int b) {
        int k0 = kt * BK;
        const unsigned short* As; int astr, ac0;
        if (k0 < TROW) { As = Tb; astr = TROW; ac0 = k0; }
        else           { As = Xb; astr = DIM;  ac0 = k0 - TROW; }
        int scol = (sgrp ^ srow) << 3;
#pragma unroll
        for (int is = 0; is < 2; ++is) {
            int rt = w * 16 + is * 8 + srow;
            int gr = m0 + rt; if (gr > N_NODES - 1) gr = N_NODES - 1;
            gload_lds16(As + (size_t)gr * astr + ac0 + scol, &At[b][(w * 16 + is * 8) * BK]);
        }
#pragma unroll
        for (int is = 0; is < 4; ++is) {
            int rt = w * 32 + is * 8 + srow;
            gload_lds16(W2 + (size_t)rt * K2 + k0 + scol, &Bt[b][(w * 32 + is * 8) * BK]);
        }
    };

    stage(0, 0);
    __syncthreads();    // drains vmcnt(0)

    for (int kt = 0; kt < NT; ++kt) {
        int cb = kt & 1;
        if (kt + 1 < NT) stage(kt + 1, cb ^ 1);   // prefetch overlaps compute below
#pragma unroll
        for (int kk = 0; kk < BK; kk += 32) {
            const int gg = (kk >> 3) + (lane >> 4);
            s16x8 af[4], bfr[4];
#pragma unroll
            for (int m = 0; m < 4; ++m) {
                int r = wr * 64 + m * 16 + (lane & 15);
                af[m] = *reinterpret_cast<const s16x8*>(&At[cb][r * BK + ((gg ^ (r & 7)) << 3)]);
            }
#pragma unroll
            for (int n = 0; n < 4; ++n) {
                int r = wc * 64 + n * 16 + (lane & 15);
                bfr[n] = *reinterpret_cast<const s16x8*>(&Bt[cb][r * BK + ((gg ^ (r & 7)) << 3)]);
            }
#pragma unroll
            for (int m = 0; m < 4; ++m)
#pragma unroll
                for (int n = 0; n < 4; ++n)
                    acc[m][n] = __builtin_amdgcn_mfma_f32_16x16x32_bf16(af[m], bfr[n], acc[m][n], 0, 0, 0);
        }
        __syncthreads();   // drains prefetch vmcnt + lds reads; buffers swap safely
    }

    // epilogue: out = acc + bias (f32 direct)
    float b4[4];
#pragma unroll
    for (int n = 0; n < 4; ++n) b4[n] = bias[wc * 64 + n * 16 + (lane & 15)];
#pragma unroll
    for (int m = 0; m < 4; ++m) {
        int rbase = m0 + wr * 64 + m * 16 + ((lane >> 4) * 4);
#pragma unroll
        for (int j = 0; j < 4; ++j) {
            int row = rbase + j;
            if (row < N_NODES) {
#pragma unroll
                for (int n = 0; n < 4; ++n) {
                    int col = wc * 64 + n * 16 + (lane & 15);
                    out[(size_t)row * DIM + col] = acc[m][n][j] + b4[n];
                }
            }
        }
    }
}

// ---------------------------------------------------------------------------
extern "C" void kernel_launch(void* const* d_in, const int* in_sizes, int n_in,
                              void* d_out, int out_size, void* d_ws, size_t ws_size,
                              hipStream_t stream) {
    const float* x      = (const float*)d_in[0];
    const int*   src    = (const int*)d_in[1];
    const int*   dst    = (const int*)d_in[2];
    const int*   etypes = (const int*)d_in[3];
    const float* basis  = (const float*)d_in[4];
    const float* comp   = (const float*)d_in[5];
    const float* loopw  = (const float*)d_in[6];
    const float* bias   = (const float*)d_in[7];
    float* out = (float*)d_out;

    char* p = (char*)d_ws;
    unsigned short* W2 = (unsigned short*)p;            p += (size_t)DIM * K2 * 2;          // 0.66 MB
    unsigned short* Xb = (unsigned short*)p;            p += (size_t)N_NODES * DIM * 2;     // 10.24 MB
    unsigned short* T  = (unsigned short*)p;            p += (size_t)N_NODES * TROW * 2;    // 40.96 MB
    int* hist    = (int*)p;                             p += (size_t)N_NODES * 4;
    int* offsets = (int*)p;                             p += (size_t)(N_NODES + 16) * 4;
    int* cursor  = (int*)p;                             p += (size_t)N_NODES * 4;
    int* sorted  = (int*)p;                             p += (size_t)N_EDGES * 4;
    int* bsum    = (int*)p;                             p += (size_t)(NB + 1) * 4;

    prep_w2<<<DIM, 256, 0, stream>>>(basis, loopw, W2);
    prep_x<<<N_NODES * DIM / 8 / 256, 256, 0, stream>>>(x, Xb);

    hipMemsetAsync(hist, 0, (size_t)N_NODES * 4, stream);
    hist_build<<<(N_EDGES + 255) / 256, 256, 0, stream>>>(dst, hist);
    hist_block_sums<<<NB, 256, 0, stream>>>(hist, bsum);
    scan_bsums<<<1, 128, 0, stream>>>(bsum);
    scan_final<<<NB, 256, 0, stream>>>(hist, bsum, offsets, cursor);
    fill_sorted<<<(N_EDGES + 255) / 256, 256, 0, stream>>>(src, dst, etypes, cursor, sorted);

    gather_T<<<N_NODES / 4, 256, 0, stream>>>(offsets, sorted, Xb, comp, T);

    gemm_out<<<(N_NODES + BM - 1) / BM, 512, 0, stream>>>(T, Xb, W2, bias, out);
}

// Round 6
// 120.592 us; speedup vs baseline: 9.0129x; 1.0163x over previous
//
#include <hip/hip_runtime.h>

// Problem constants (match reference)
#define N_NODES 20000
#define N_EDGES 300000
#define DIM 256
#define NUM_RELS 8
#define NUM_BASES 4
#define NB 79               // (N_NODES + 255) / 256
#define K2 1280             // GEMM K: 4 basis blocks (1024) + x block (256)
#define TROW 1024           // T row length (4 * 256)
#define PREPX_BLOCKS 2500   // N_NODES * DIM / 8 / 256

typedef float f32x4 __attribute__((ext_vector_type(4)));
typedef short s16x8 __attribute__((ext_vector_type(8)));

__device__ __forceinline__ unsigned short f2bf(float f) {
    unsigned u = __builtin_bit_cast(unsigned, f);
    u += 0x7fffu + ((u >> 16) & 1u);          // round-to-nearest-even
    return (unsigned short)(u >> 16);
}
__device__ __forceinline__ float bf2f(unsigned short h) {
    unsigned u = ((unsigned)h) << 16;
    return __builtin_bit_cast(float, u);
}

__device__ __forceinline__ void gload_lds16(const void* g, void* l) {
    __builtin_amdgcn_global_load_lds((const __attribute__((address_space(1))) void*)g,
                                     (__attribute__((address_space(3))) void*)l,
                                     16, 0, 0);
}

// ---------------------------------------------------------------------------
// K1 (fused prep): blocks [0, 2500): x f32 -> bf16 (8 elems/thread)
//                  blocks [2500, 2756): W2[o][k] bf16
//   W2: k = b*256+i -> basis[b][i][o];  k = 1024+i -> loop_weight[i][o]
// ---------------------------------------------------------------------------
__global__ __launch_bounds__(256) void prep_all(const float* __restrict__ x,
                                                const float* __restrict__ basis,
                                                const float* __restrict__ loopw,
                                                unsigned short* __restrict__ xb,
                                                unsigned short* __restrict__ W2) {
    int blk = blockIdx.x;
    if (blk < PREPX_BLOCKS) {
        int idx = (blk * 256 + threadIdx.x) * 8;
        float4 v0 = *reinterpret_cast<const float4*>(x + idx);
        float4 v1 = *reinterpret_cast<const float4*>(x + idx + 4);
        s16x8 o;
        o[0] = (short)f2bf(v0.x); o[1] = (short)f2bf(v0.y);
        o[2] = (short)f2bf(v0.z); o[3] = (short)f2bf(v0.w);
        o[4] = (short)f2bf(v1.x); o[5] = (short)f2bf(v1.y);
        o[6] = (short)f2bf(v1.z); o[7] = (short)f2bf(v1.w);
        *reinterpret_cast<s16x8*>(xb + idx) = o;
    } else {
        int o = blk - PREPX_BLOCKS;   // 0..255
        int i = threadIdx.x;          // 0..255
#pragma unroll
        for (int b = 0; b < NUM_BASES; ++b)
            W2[(size_t)o * K2 + b * 256 + i] = f2bf(basis[((size_t)b * 256 + i) * 256 + o]);
        W2[(size_t)o * K2 + 1024 + i] = f2bf(loopw[(size_t)i * 256 + o]);
    }
}

// ---------------------------------------------------------------------------
// Sort chain: zero -> histogram by dst -> hierarchical scan -> fill sorted
// ---------------------------------------------------------------------------
__global__ __launch_bounds__(256) void hist_zero(int* __restrict__ hist) {
    int i = blockIdx.x * 256 + threadIdx.x;
    if (i < N_NODES) hist[i] = 0;
}

__global__ __launch_bounds__(256) void hist_build(const int* __restrict__ dst,
                                                  int* __restrict__ hist) {
    int e = blockIdx.x * 256 + threadIdx.x;
    if (e < N_EDGES) atomicAdd(&hist[dst[e]], 1);
}

__global__ __launch_bounds__(256) void hist_block_sums(const int* __restrict__ hist,
                                                       int* __restrict__ bsum) {
    int i = blockIdx.x * 256 + threadIdx.x;
    int v = (i < N_NODES) ? hist[i] : 0;
#pragma unroll
    for (int off = 32; off; off >>= 1) v += __shfl_down(v, off, 64);
    __shared__ int ws[4];
    if ((threadIdx.x & 63) == 0) ws[threadIdx.x >> 6] = v;
    __syncthreads();
    if (threadIdx.x == 0) bsum[blockIdx.x] = ws[0] + ws[1] + ws[2] + ws[3];
}

__global__ __launch_bounds__(128) void scan_bsums(int* __restrict__ bsum) {
    __shared__ int s[128];
    int t = threadIdx.x;
    int v = (t < NB) ? bsum[t] : 0;
    s[t] = v;
    __syncthreads();
    for (int off = 1; off < 128; off <<= 1) {
        int a = (t >= off) ? s[t - off] : 0;
        __syncthreads();
        s[t] += a;
        __syncthreads();
    }
    if (t < NB) bsum[t] = s[t] - v;   // exclusive
}

__global__ __launch_bounds__(256) void scan_final(const int* __restrict__ hist,
                                                  const int* __restrict__ bsum,
                                                  int* __restrict__ offsets,
                                                  int* __restrict__ cursor) {
    __shared__ int s[256];
    int t = threadIdx.x;
    int i = blockIdx.x * 256 + t;
    int v = (i < N_NODES) ? hist[i] : 0;
    s[t] = v;
    __syncthreads();
    for (int off = 1; off < 256; off <<= 1) {
        int a = (t >= off) ? s[t - off] : 0;
        __syncthreads();
        s[t] += a;
        __syncthreads();
    }
    int excl = s[t] - v + bsum[blockIdx.x];
    if (i < N_NODES) {
        offsets[i] = excl;
        cursor[i] = excl;
    }
    if (i == N_NODES - 1) offsets[N_NODES] = N_EDGES;
}

__global__ __launch_bounds__(256) void fill_sorted(const int* __restrict__ src,
                                                   const int* __restrict__ dst,
                                                   const int* __restrict__ et,
                                                   int* __restrict__ cursor,
                                                   int* __restrict__ sorted) {
    int e = blockIdx.x * 256 + threadIdx.x;
    if (e >= N_EDGES) return;
    int pos = atomicAdd(&cursor[dst[e]], 1);
    sorted[pos] = src[e] * NUM_RELS + et[e];
}

// ---------------------------------------------------------------------------
// K3: gather: T[d, b*256+j] = sum_{e->d} comp[et_e, b] * x_bf16[src_e, j]
// One wave per node; each lane covers 4 consecutive j; acc[4 bases][4] in regs.
// ---------------------------------------------------------------------------
__global__ __launch_bounds__(256) void gather_T(const int* __restrict__ offsets,
                                                const int* __restrict__ sorted,
                                                const unsigned short* __restrict__ Xb,
                                                const float* __restrict__ comp,
                                                unsigned short* __restrict__ T) {
    int n = blockIdx.x * 4 + (threadIdx.x >> 6);   // grid exact: 5000 blocks
    int lane = threadIdx.x & 63;
    int c = lane * 4;

    float acc[NUM_BASES][4] = {};
    int beg = offsets[n], end = offsets[n + 1];
    int e = beg;
    for (; e + 1 < end; e += 2) {
        int p0 = sorted[e], p1 = sorted[e + 1];
        ushort4 v0 = *reinterpret_cast<const ushort4*>(Xb + (size_t)(p0 >> 3) * DIM + c);
        ushort4 v1 = *reinterpret_cast<const ushort4*>(Xb + (size_t)(p1 >> 3) * DIM + c);
        float4 c0 = *reinterpret_cast<const float4*>(comp + (p0 & 7) * 4);
        float4 c1 = *reinterpret_cast<const float4*>(comp + (p1 & 7) * 4);
        float x0[4] = {bf2f(v0.x), bf2f(v0.y), bf2f(v0.z), bf2f(v0.w)};
        float x1[4] = {bf2f(v1.x), bf2f(v1.y), bf2f(v1.z), bf2f(v1.w)};
        float cw0[4] = {c0.x, c0.y, c0.z, c0.w};
        float cw1[4] = {c1.x, c1.y, c1.z, c1.w};
#pragma unroll
        for (int b = 0; b < NUM_BASES; ++b)
#pragma unroll
            for (int j = 0; j < 4; ++j)
                acc[b][j] += cw0[b] * x0[j] + cw1[b] * x1[j];
    }
    if (e < end) {
        int p0 = sorted[e];
        ushort4 v0 = *reinterpret_cast<const ushort4*>(Xb + (size_t)(p0 >> 3) * DIM + c);
        float4 c0 = *reinterpret_cast<const float4*>(comp + (p0 & 7) * 4);
        float x0[4] = {bf2f(v0.x), bf2f(v0.y), bf2f(v0.z), bf2f(v0.w)};
        float cw0[4] = {c0.x, c0.y, c0.z, c0.w};
#pragma unroll
        for (int b = 0; b < NUM_BASES; ++b)
#pragma unroll
            for (int j = 0; j < 4; ++j)
                acc[b][j] += cw0[b] * x0[j];
    }
#pragma unroll
    for (int b = 0; b < NUM_BASES; ++b) {
        ushort4 o;
        o.x = f2bf(acc[b][0]); o.y = f2bf(acc[b][1]);
        o.z = f2bf(acc[b][2]); o.w = f2bf(acc[b][3]);
        *reinterpret_cast<ushort4*>(T + (size_t)n * TROW + b * 256 + c) = o;
    }
}

// ---------------------------------------------------------------------------
// K4: out[m, o] = sum_k A[m, k] * W2[o, k] + bias[o]
//   A = [T | x_bf16] (K=1280, source switch at k=1024).
// 128x256 tile (one N block), BK=64, 512 threads (8 waves 2x4),
// global_load_lds + XOR swizzle, 2-phase double-buffered LDS.
// ---------------------------------------------------------------------------
#define BM 128
#define BN 256
#define BK 64
#define NT 20   // K2 / BK

__global__ __launch_bounds__(512) void gemm_out(const unsigned short* __restrict__ Tb,
                                                const unsigned short* __restrict__ Xb,
                                                const unsigned short* __restrict__ W2,
                                                const float* __restrict__ bias,
                                                float* __restrict__ out) {
    __shared__ unsigned short At[2][BM * BK];   // 2 x 16KB
    __shared__ unsigned short Bt[2][BN * BK];   // 2 x 32KB
    const int m0 = blockIdx.x * BM;
    const int t = threadIdx.x;
    const int lane = t & 63;
    const int w = t >> 6;            // 0..7
    const int wr = w >> 2;           // 0..1
    const int wc = w & 3;            // 0..3
    const int srow = lane >> 3;      // 0..7
    const int sgrp = lane & 7;       // 0..7

    f32x4 acc[4][4] = {};

    auto stage = [&](int kt, int b) {
        int k0 = kt * BK;
        const unsigned short* As; int astr, ac0;
        if (k0 < TROW) { As = Tb; astr = TROW; ac0 = k0; }
        else           { As = Xb; astr = DIM;  ac0 = k0 - TROW; }
        int scol = (sgrp ^ srow) << 3;
#pragma unroll
        for (int is = 0; is < 2; ++is) {
            int rt = w * 16 + is * 8 + srow;
            int gr = m0 + rt; if (gr > N_NODES - 1) gr = N_NODES - 1;
            gload_lds16(As + (size_t)gr * astr + ac0 + scol, &At[b][(w * 16 + is * 8) * BK]);
        }
#pragma unroll
        for (int is = 0; is < 4; ++is) {
            int rt = w * 32 + is * 8 + srow;
            gload_lds16(W2 + (size_t)rt * K2 + k0 + scol, &Bt[b][(w * 32 + is * 8) * BK]);
        }
    };

    stage(0, 0);
    __syncthreads();    // drains vmcnt(0)

    for (int kt = 0; kt < NT; ++kt) {
        int cb = kt & 1;
        if (kt + 1 < NT) stage(kt + 1, cb ^ 1);   // prefetch overlaps compute below
#pragma unroll
        for (int kk = 0; kk < BK; kk += 32) {
            const int gg = (kk >> 3) + (lane >> 4);
            s16x8 af[4], bfr[4];
#pragma unroll
            for (int m = 0; m < 4; ++m) {
                int r = wr * 64 + m * 16 + (lane & 15);
                af[m] = *reinterpret_cast<const s16x8*>(&At[cb][r * BK + ((gg ^ (r & 7)) << 3)]);
            }
#pragma unroll
            for (int n = 0; n < 4; ++n) {
                int r = wc * 64 + n * 16 + (lane & 15);
                bfr[n] = *reinterpret_cast<const s16x8*>(&Bt[cb][r * BK + ((gg ^ (r & 7)) << 3)]);
            }
#pragma unroll
            for (int m = 0; m < 4; ++m)
#pragma unroll
                for (int n = 0; n < 4; ++n)
                    acc[m][n] = __builtin_amdgcn_mfma_f32_16x16x32_bf16(af[m], bfr[n], acc[m][n], 0, 0, 0);
        }
        __syncthreads();   // drains prefetch vmcnt + lds reads; buffers swap safely
    }

    // epilogue: out = acc + bias (f32 direct)
    float b4[4];
#pragma unroll
    for (int n = 0; n < 4; ++n) b4[n] = bias[wc * 64 + n * 16 + (lane & 15)];
#pragma unroll
    for (int m = 0; m < 4; ++m) {
        int rbase = m0 + wr * 64 + m * 16 + ((lane >> 4) * 4);
#pragma unroll
        for (int j = 0; j < 4; ++j) {
            int row = rbase + j;
            if (row < N_NODES) {
#pragma unroll
                for (int n = 0; n < 4; ++n) {
                    int col = wc * 64 + n * 16 + (lane & 15);
                    out[(size_t)row * DIM + col] = acc[m][n][j] + b4[n];
                }
            }
        }
    }
}

// ---------------------------------------------------------------------------
extern "C" void kernel_launch(void* const* d_in, const int* in_sizes, int n_in,
                              void* d_out, int out_size, void* d_ws, size_t ws_size,
                              hipStream_t stream) {
    const float* x      = (const float*)d_in[0];
    const int*   src    = (const int*)d_in[1];
    const int*   dst    = (const int*)d_in[2];
    const int*   etypes = (const int*)d_in[3];
    const float* basis  = (const float*)d_in[4];
    const float* comp   = (const float*)d_in[5];
    const float* loopw  = (const float*)d_in[6];
    const float* bias   = (const float*)d_in[7];
    float* out = (float*)d_out;

    char* p = (char*)d_ws;
    unsigned short* W2 = (unsigned short*)p;            p += (size_t)DIM * K2 * 2;          // 0.66 MB
    unsigned short* Xb = (unsigned short*)p;            p += (size_t)N_NODES * DIM * 2;     // 10.24 MB
    unsigned short* T  = (unsigned short*)p;            p += (size_t)N_NODES * TROW * 2;    // 40.96 MB
    int* hist    = (int*)p;                             p += (size_t)N_NODES * 4;
    int* offsets = (int*)p;                             p += (size_t)(N_NODES + 16) * 4;
    int* cursor  = (int*)p;                             p += (size_t)N_NODES * 4;
    int* sorted  = (int*)p;                             p += (size_t)N_EDGES * 4;
    int* bsum    = (int*)p;                             p += (size_t)(NB + 1) * 4;

    prep_all<<<PREPX_BLOCKS + DIM, 256, 0, stream>>>(x, basis, loopw, Xb, W2);

    hist_zero<<<NB, 256, 0, stream>>>(hist);
    hist_build<<<(N_EDGES + 255) / 256, 256, 0, stream>>>(dst, hist);
    hist_block_sums<<<NB, 256, 0, stream>>>(hist, bsum);
    scan_bsums<<<1, 128, 0, stream>>>(bsum);
    scan_final<<<NB, 256, 0, stream>>>(hist, bsum, offsets, cursor);
    fill_sorted<<<(N_EDGES + 255) / 256, 256, 0, stream>>>(src, dst, etypes, cursor, sorted);

    gather_T<<<N_NODES / 4, 256, 0, stream>>>(offsets, sorted, Xb, comp, T);

    gemm_out<<<(N_NODES + BM - 1) / BM, 512, 0, stream>>>(T, Xb, W2, bias, out);
}